// Round 11
// baseline (1782.548 us; speedup 1.0000x reference)
//
#include <hip/hip_runtime.h>

// ---------------------------------------------------------------------------
// RNN (LSTM) + CRF loss on MI355X — round 11.
// LSTM: r6-proven protocol (flag handshake, counted-vmcnt chunk pipeline,
// 192-VGPR register-resident weights, 32x32x16 swapped MFMA) with two
// changes: (1) h exchanged in FRAGMENT-MAJOR layout -> every consumer load
// is a coalesced 1KB transaction (was 32 scattered lines), producer stores
// contiguous 512B (was 32 lines); (2) per-wave flags (128), no syncthreads.
// em_gemm: one block per t, stages hxch[t] (64KB) into LDS, 16x16x32 math.
// CRF: r10 E-precompute version (proven).
// ---------------------------------------------------------------------------

typedef float f32x4 __attribute__((ext_vector_type(4)));
typedef float f32x16 __attribute__((ext_vector_type(16)));
typedef __bf16 bf16x8 __attribute__((ext_vector_type(8)));
typedef unsigned int u32x4 __attribute__((ext_vector_type(4)));
typedef unsigned int u32x2 __attribute__((ext_vector_type(2)));

#define T_LEN 256
#define BB    64
#define EE    256
#define HH    512
#define KK    128
#define KCAT  768   // E + H

static __device__ inline unsigned f2bf(float f) {
  union { float f; unsigned u; } v; v.f = f;
  unsigned r = v.u + 0x7FFF + ((v.u >> 16) & 1);   // round-nearest-even
  return r >> 16;
}
static __device__ inline float sigm(float x) { return 1.f / (1.f + __expf(-x)); }
static __device__ inline float tanh_fast(float x) {
  return 1.f - 2.f / (1.f + __expf(2.f * x));      // safe at +/-inf
}
static __device__ inline bf16x8 ubf(u32x4 v) {
  union { u32x4 u; bf16x8 b; } c; c.u = v; return c.b;
}

// --- 1. weight conversion (LDS tile transpose, coalesced both sides) -------
__global__ __launch_bounds__(256) void build_wcat(
    const float* __restrict__ Wi, const float* __restrict__ Wh,
    unsigned short* __restrict__ WcatT) {
  __shared__ float tile[64][65];
  int ct = blockIdx.x & 31, kt = blockIdx.x >> 5;    // 32 c-tiles x 12 k-tiles
  int tc = threadIdx.x & 63, tr = threadIdx.x >> 6;
  int c0 = ct * 64, k0 = kt * 64;
#pragma unroll
  for (int i = 0; i < 16; ++i) {
    int r = tr * 16 + i, k = k0 + r;
    float v = (k < EE) ? Wi[(size_t)k * 2048 + c0 + tc]
                       : Wh[(size_t)(k - EE) * 2048 + c0 + tc];
    tile[r][tc] = v;
  }
  __syncthreads();
#pragma unroll
  for (int i = 0; i < 16; ++i) {
    int cL = tr * 16 + i;
    WcatT[(size_t)(c0 + cL) * KCAT + k0 + tc] = (unsigned short)f2bf(tile[tc][cL]);
  }
}

__global__ __launch_bounds__(256) void build_wout(
    const float* __restrict__ Wout, unsigned short* __restrict__ WoutT) {
  __shared__ float tile[64][65];
  int ct = blockIdx.x & 1, kt = blockIdx.x >> 1;     // 2 c-tiles x 8 k-tiles
  int tc = threadIdx.x & 63, tr = threadIdx.x >> 6;
  int c0 = ct * 64, k0 = kt * 64;
#pragma unroll
  for (int i = 0; i < 16; ++i) {
    int r = tr * 16 + i;
    tile[r][tc] = Wout[(size_t)(k0 + r) * KK + c0 + tc];
  }
  __syncthreads();
#pragma unroll
  for (int i = 0; i < 16; ++i) {
    int cL = tr * 16 + i;
    WoutT[(size_t)(c0 + cL) * HH + k0 + tc] = (unsigned short)f2bf(tile[tc][cL]);
  }
}

// --- 2. embedding ----------------------------------------------------------
__global__ __launch_bounds__(256) void embed_kernel(
    const int* __restrict__ wx, const int* __restrict__ cx,
    const float* __restrict__ we, const float* __restrict__ ce,
    unsigned short* __restrict__ x) {
  int bid = blockIdx.x;             // t*64 + b
  int t = bid >> 6, b = bid & 63;
  int e = threadIdx.x;              // 0..255
  int w = wx[b * T_LEN + t];
  float v = we[(size_t)w * EE + e];
  const int* cp = cx + ((size_t)(b * T_LEN + t)) * 8;
  float s = 0.f;
#pragma unroll
  for (int l = 0; l < 8; ++l) s += ce[(size_t)cp[l] * EE + e];
  v += s * 0.125f;
  x[(size_t)bid * EE + e] = (unsigned short)f2bf(v);
}

// --- 3. flag reset (sc0 sc1 so LLC-bypass poll loads see the zeros) --------
__global__ void zero_flags(unsigned int* __restrict__ f) {   // 128 dwords
  unsigned z = 0u;
  asm volatile("global_store_dword %0, %1, off sc0 sc1"
               :: "v"(f + threadIdx.x), "v"(z) : "memory");
}

// --- 4. persistent LSTM ----------------------------------------------------
#define SBAR __builtin_amdgcn_sched_barrier(0)
#define WAITV(N) do { asm volatile("s_waitcnt vmcnt(" #N ")" ::: "memory"); SBAR; } while (0)
#define LDC(dst, ptr, OFF) \
  asm volatile("global_load_dwordx4 %0, %1, off offset:" OFF " sc0 sc1" \
               : "=v"(dst) : "v"(ptr) : "memory")
#define LDN(dst, ptr, OFF) \
  asm volatile("global_load_dwordx4 %0, %1, off offset:" OFF \
               : "=v"(dst) : "v"(ptr) : "memory")

#define ISSUE_X(B, P) do { \
  LDN(B[0],P,"0");   LDN(B[1],P,"32");  LDN(B[2],P,"64");  LDN(B[3],P,"96"); \
  LDN(B[4],P,"128"); LDN(B[5],P,"160"); LDN(B[6],P,"192"); LDN(B[7],P,"224"); \
  LDN(B[8],P,"256"); LDN(B[9],P,"288"); LDN(B[10],P,"320"); LDN(B[11],P,"352"); \
  LDN(B[12],P,"384"); LDN(B[13],P,"416"); LDN(B[14],P,"448"); LDN(B[15],P,"480"); } while (0)

// h fragment loads: frag j at hb + j*1024, coalesced 1KB each (lane*16 in base)
#define ISSUE_HG(B, P0, P1, P2, P3) do { \
  LDC(B[0],P0,"0"); LDC(B[1],P0,"1024"); LDC(B[2],P0,"2048"); LDC(B[3],P0,"3072"); \
  LDC(B[4],P1,"0"); LDC(B[5],P1,"1024"); LDC(B[6],P1,"2048"); LDC(B[7],P1,"3072"); \
  LDC(B[8],P2,"0"); LDC(B[9],P2,"1024"); LDC(B[10],P2,"2048"); LDC(B[11],P2,"3072"); \
  LDC(B[12],P3,"0"); LDC(B[13],P3,"1024"); LDC(B[14],P3,"2048"); LDC(B[15],P3,"3072"); } while (0)

// wave = 32 batches x 32 z-cols (32x32x16 swapped MFMA, D = Wfrag x Hfrag).
// D: col = lane&31 (batch), row = (reg&3) + 8*(reg>>2) + 4*(lane>>5)
//    = gate*8 + uoff  -> acc[g*4+r] = gate g, u = u0 + 4*hi + r.
// hxch layout: cell(bh, j, L) = 16B = h[bh*32+(L&31)][j*16+(L>>5)*8 .. +8];
// consumer frag-j load = 64 lanes x contiguous 16B; producer wave writes
// contiguous 512B. Per-wave flags; waves fully independent (no LDS).
__global__ __launch_bounds__(128, 1) void lstm_persistent(
    const unsigned short* __restrict__ x,      // [T][64][256] bf16
    unsigned short* __restrict__ hxch,         // [256][2][32][64] 16B cells
    const unsigned short* __restrict__ WcatT,  // [2048][768] bf16
    const float* __restrict__ bias,            // [2048]
    const int* __restrict__ wx,                // [64][256]
    unsigned int* __restrict__ flags) {        // 128 packed dwords (per wave)
  const int tid = threadIdx.x;
  const int lane = tid & 63;
  const int bhalf = tid >> 6;                  // 2 independent waves
  const int hi = lane >> 5;
  const int batch = bhalf * 32 + (lane & 31);
  const int bid = blockIdx.x;
  const int u0 = bid * 8;                      // block's u-slice [u0, u0+8)
  const int rr = lane & 31;                    // A-frag row = z-col id
  const int wcol = (rr >> 3) * HH + u0 + (rr & 7);   // gate*512 + u0 + uoff

  // 48 loop-invariant weight A-frags -> 192 VGPRs
  bf16x8 wreg[48];
#pragma unroll
  for (int kf = 0; kf < 48; ++kf)
    wreg[kf] = *(const bf16x8*)(WcatT + (size_t)wcol * KCAT + kf * 16 + hi * 8);

  float bv[16];
#pragma unroll
  for (int q = 0; q < 4; ++q)
#pragma unroll
    for (int r = 0; r < 4; ++r)
      bv[q * 4 + r] = bias[q * HH + u0 + 4 * hi + r];

  const char* xlane = (const char*)x + ((size_t)batch * EE + hi * 8) * 2;
  // consumer read base: cell(bhalf, j, lane) -> + lane*16, frag j at +j*1024
  const char* hread = (const char*)hxch + (size_t)bhalf * 32768 + (size_t)lane * 16;
  // producer write: cell(bhalf, bid>>1, (lane&31) + 32*(bid&1)), byte +hi*8
  char* hstore = (char*)hxch + (size_t)bhalf * 32768 + (size_t)(bid >> 1) * 1024 +
                 ((size_t)((lane & 31) + 32 * (bid & 1))) * 16 + hi * 8;
  const int* wxp = wx + batch * T_LEN;
  unsigned int* myflag = flags + bid * 2 + bhalf;

  float cst[4] = {0.f, 0.f, 0.f, 0.f};
  float hst[4] = {0.f, 0.f, 0.f, 0.f};
  u32x4 bufX[16], bufH[16];
  unsigned wxv;
  f32x16 acc;

  // ---- t = 0 (h = 0: x-part only) ----
  ISSUE_X(bufX, xlane);
  asm volatile("global_load_dword %0, %1, off" : "=v"(wxv) : "v"(wxp) : "memory");
  WAITV(0);
#pragma unroll
  for (int i = 0; i < 16; ++i) acc[i] = bv[i];
#pragma unroll
  for (int kf = 0; kf < 16; ++kf)
    acc = __builtin_amdgcn_mfma_f32_32x32x16_bf16(wreg[kf], ubf(bufX[kf]), acc, 0, 0, 0);
  {
    bool mk = ((int)wxv) > 0;
#pragma unroll
    for (int r = 0; r < 4; ++r) {
      float zi = acc[r], zf = acc[4 + r], zg = acc[8 + r], zo = acc[12 + r];
      float cn = sigm(zf) * cst[r] + sigm(zi) * tanh_fast(zg);
      float hn = sigm(zo) * tanh_fast(cn);
      if (mk) { cst[r] = cn; hst[r] = hn; }
    }
    u32x2 ph;
    ph[0] = f2bf(hst[0]) | (f2bf(hst[1]) << 16);
    ph[1] = f2bf(hst[2]) | (f2bf(hst[3]) << 16);
    asm volatile("global_store_dwordx2 %0, %1, off sc0 sc1"
                 :: "v"(hstore), "v"(ph) : "memory");
  }
  WAITV(0);                                    // own h[1] ack'd at LLC
  __hip_atomic_store(myflag, 1u, __ATOMIC_RELAXED, __HIP_MEMORY_SCOPE_AGENT);

  // ---- t = 1..255 ----
  for (int t = 1; t < T_LEN; ++t) {
    const char* xt = xlane + (size_t)t * 32768;
    const char* hb0 = hread + (size_t)(t - 1) * 65536;
    const char* hb1 = hb0 + 4096;
    const char* hb2 = hb0 + 8192;
    const char* hb3 = hb0 + 12288;
    const char* hb4 = hb0 + 16384;
    const char* hb5 = hb0 + 20480;
    const char* hb6 = hb0 + 24576;
    const char* hb7 = hb0 + 28672;

    ISSUE_X(bufX, xt);
    asm volatile("global_load_dword %0, %1, off" : "=v"(wxv) : "v"(wxp + t) : "memory");
    // poll 128 per-wave flags: one coalesced dwordx2 per lane
    {
      u32x2 fv; int it = 0;
      for (;;) {
        asm volatile("global_load_dwordx2 %0, %1, off sc0 sc1\n\ts_waitcnt vmcnt(0)"
                     : "=v"(fv) : "v"(flags + lane * 2) : "memory");
        if (__all((int)(fv[0] >= (unsigned)t && fv[1] >= (unsigned)t))) break;
        if (++it >= (1 << 20)) break;          // bailout: fail visibly, never hang
      }
      SBAR;
    }
    ISSUE_HG(bufH, hb0, hb1, hb2, hb3);        // h frags 0-15 in flight
#pragma unroll
    for (int i = 0; i < 16; ++i) acc[i] = bv[i];
#pragma unroll
    for (int kf = 0; kf < 16; ++kf)            // x-part (data arrived: poll drained)
      acc = __builtin_amdgcn_mfma_f32_32x32x16_bf16(wreg[kf], ubf(bufX[kf]), acc, 0, 0, 0);
    SBAR;
    ISSUE_HG(bufX, hb4, hb5, hb6, hb7);        // h frags 16-31 reuse x buffer
    WAITV(16);                                 // frags 0-15 arrived
#pragma unroll
    for (int kf = 0; kf < 16; ++kf)
      acc = __builtin_amdgcn_mfma_f32_32x32x16_bf16(wreg[16 + kf], ubf(bufH[kf]), acc, 0, 0, 0);
    WAITV(0);                                  // frags 16-31 arrived
#pragma unroll
    for (int kf = 0; kf < 16; ++kf)
      acc = __builtin_amdgcn_mfma_f32_32x32x16_bf16(wreg[32 + kf], ubf(bufX[kf]), acc, 0, 0, 0);

    bool mk = ((int)wxv) > 0;
#pragma unroll
    for (int r = 0; r < 4; ++r) {
      float zi = acc[r], zf = acc[4 + r], zg = acc[8 + r], zo = acc[12 + r];
      float cn = sigm(zf) * cst[r] + sigm(zi) * tanh_fast(zg);
      float hn = sigm(zo) * tanh_fast(cn);
      if (mk) { cst[r] = cn; hst[r] = hn; }
    }
    u32x2 ph;
    ph[0] = f2bf(hst[0]) | (f2bf(hst[1]) << 16);
    ph[1] = f2bf(hst[2]) | (f2bf(hst[3]) << 16);
    asm volatile("global_store_dwordx2 %0, %1, off sc0 sc1"
                 :: "v"(hstore + (size_t)t * 65536), "v"(ph) : "memory");
    WAITV(0);                                  // own h[t+1] ack'd at LLC
    __hip_atomic_store(myflag, (unsigned)(t + 1),
                       __ATOMIC_RELAXED, __HIP_MEMORY_SCOPE_AGENT);
  }
}

// --- 5. emissions GEMM: 256 blocks (one t) x 512 thr ------------------------
// Stage hxch[t] (64KB, fragment-major) into LDS coalesced; 16x16x32 math with
// A-frags from LDS; B = WoutT (L2-hot); em writes row-major (unchanged).
__global__ __launch_bounds__(512) void em_gemm(
    const unsigned short* __restrict__ hxch,  // [256][2][32][64] 16B cells
    const unsigned short* __restrict__ WoutT, // [128][512] bf16
    const float* __restrict__ bout,
    const int* __restrict__ wx,
    float* __restrict__ em) {                 // [16384][128]
  __shared__ unsigned short hl[32768];        // 64 KB
  int t = blockIdx.x;
  int tid = threadIdx.x;
  const char* src = (const char*)hxch + (size_t)t * 65536;
#pragma unroll
  for (int i = 0; i < 8; ++i)
    *(u32x4*)(&hl[(size_t)(i * 512 + tid) * 8]) =
        *(const u32x4*)(src + (size_t)(i * 512 + tid) * 16);
  __syncthreads();

  int wave = tid >> 6, lane = tid & 63;
  int m = wave >> 1, nh = wave & 1;
  int arow = lane & 15, l4 = lane >> 4;       // 0..3
  int b = m * 16 + arow;
  // cell(bh=b>>5, j=2*ks+(l4>>1), L=(b&31)+32*(l4&1)) : h[b][ks*32 + l4*8 ..]
  int cb = (b >> 5) * 2048 + (b & 31) + 32 * (l4 & 1) + (l4 >> 1) * 64;
  f32x4 acc[4];
#pragma unroll
  for (int nt = 0; nt < 4; ++nt) acc[nt] = (f32x4){0.f, 0.f, 0.f, 0.f};
#pragma unroll
  for (int ks = 0; ks < 16; ++ks) {
    bf16x8 a = *(const bf16x8*)(&hl[(size_t)(cb + ks * 128) * 8]);
#pragma unroll
    for (int nt = 0; nt < 4; ++nt) {
      const unsigned short* Bp =
          WoutT + (size_t)(nh * 64 + nt * 16 + arow) * HH + l4 * 8 + ks * 32;
      acc[nt] = __builtin_amdgcn_mfma_f32_16x16x32_bf16(a, *(const bf16x8*)Bp, acc[nt], 0, 0, 0);
    }
  }
#pragma unroll
  for (int nt = 0; nt < 4; ++nt) {
    int n = nh * 64 + nt * 16 + arow;
    float bo = bout[n];
#pragma unroll
    for (int r = 0; r < 4; ++r) {
      int row = t * 64 + m * 16 + l4 * 4 + r;
      int bb = row & 63;
      float v = (acc[nt][r] + bo) * ((wx[bb * T_LEN + t] > 0) ? 1.f : 0.f);
      em[(size_t)row * KK + n] = v;
    }
  }
}

// --- 6. CRF forward + gold — E-precompute version (r10, proven) -------------
__global__ __launch_bounds__(512) void crf_kernel(
    const float* __restrict__ em,             // [256][64][128]
    const float* __restrict__ trans,          // [128][128]
    const int* __restrict__ wx,
    const int* __restrict__ y,                // [64][257]
    float* __restrict__ out) {
  int b = blockIdx.x;
  __shared__ float tl[KK][129];
  __shared__ float El[KK][129];
  __shared__ float sc[KK];
  __shared__ float p[KK];
  __shared__ float red[512];
  __shared__ float red2[512];
  __shared__ float mshare[2];
  int tid = threadIdx.x;
  for (int i = tid; i < KK * KK; i += 512) {
    float v = trans[i];
    tl[i >> 7][i & 127] = v;
    El[i >> 7][i & 127] = __expf(v);          // exp(-1e4) = 0
  }
  if (tid < KK) sc[tid] = (tid == 1) ? 0.f : -10000.f;
  __syncthreads();

  int k = tid & 127, q = tid >> 7, j0 = q * 32;
  float msc = 0.f;                             // max_k sc (k=SOS is 0)

  for (int t = 0; t < T_LEN; ++t) {
    if (wx[b * T_LEN + t] <= 0) continue;      // block-uniform
    if (tid < KK) p[tid] = __expf(sc[tid] - msc);
    __syncthreads();
    float S = 0.f;
#pragma unroll
    for (int j = 0; j < 32; ++j) S += El[k][j0 + j] * p[j0 + j];
    red[tid] = S;
    __syncthreads();
    if (q == 0) {                              // waves 0,1: k = 0..127
      float Sk = S + red[128 + k] + red[256 + k] + red[384 + k];
      float ns = em[(size_t)(t * BB + b) * KK + k] + msc + __logf(Sk);
      sc[k] = ns;
      float m = ns;                            // wave max over 64 lanes
#pragma unroll
      for (int off = 32; off; off >>= 1) m = fmaxf(m, __shfl_xor(m, off));
      if ((tid & 63) == 0) mshare[tid >> 6] = m;
    }
    __syncthreads();
    msc = fmaxf(mshare[0], mshare[1]);
  }

  // gold score
  float term = 0.f, cnt = 0.f;
  if (tid < T_LEN) {
    int yp = y[b * 257 + tid], yn = y[b * 257 + tid + 1];
    if (wx[b * T_LEN + tid] > 0) {
      term = em[(size_t)(tid * BB + b) * KK + yn] + tl[yn][yp];
      cnt = 1.f;
    }
  }
  red[tid] = term; red2[tid] = cnt;
  __syncthreads();
  for (int s2 = 256; s2 > 0; s2 >>= 1) {
    if (tid < s2) { red[tid] += red[tid + s2]; red2[tid] += red2[tid + s2]; }
    __syncthreads();
  }
  float gold = red[0];
  int len = (int)(red2[0] + 0.5f);
  __syncthreads();

  // Z = LSE_k(sc[k] + trans[EOS][k])
  float v = (tid < KK) ? sc[tid] + tl[2][tid] : -3.0e38f;
  red[tid] = v;
  __syncthreads();
  for (int s2 = 256; s2 > 0; s2 >>= 1) {
    if (tid < s2) red[tid] = fmaxf(red[tid], red[tid + s2]);
    __syncthreads();
  }
  float mz = red[0];
  __syncthreads();
  red[tid] = (tid < KK) ? __expf(v - mz) : 0.f;
  __syncthreads();
  for (int s2 = 256; s2 > 0; s2 >>= 1) {
    if (tid < s2) red[tid] += red[tid + s2];
    __syncthreads();
  }
  if (tid == 0) {
    float Z = mz + __logf(red[0]);
    int last_tag = y[b * 257 + len];
    out[b] = Z - (gold + tl[2][last_tag]);
  }
}

// ---------------------------------------------------------------------------
extern "C" void kernel_launch(void* const* d_in, const int* in_sizes, int n_in,
                              void* d_out, int out_size, void* d_ws, size_t ws_size,
                              hipStream_t stream) {
  const int*   cx    = (const int*)d_in[0];
  const int*   wx    = (const int*)d_in[1];
  const int*   y     = (const int*)d_in[2];
  const float* ce    = (const float*)d_in[3];
  const float* we    = (const float*)d_in[4];
  const float* Wi    = (const float*)d_in[5];
  const float* Wh    = (const float*)d_in[6];
  const float* bias  = (const float*)d_in[7];
  const float* Wout  = (const float*)d_in[8];
  const float* bout  = (const float*)d_in[9];
  const float* trans = (const float*)d_in[10];
  float* out = (float*)d_out;

  char* ws = (char*)d_ws;
  // ws layout (16B aligned), ~28.5 MB; em aliases x (x dead after lstm)
  unsigned short* WcatT = (unsigned short*)(ws + 0);          //  3,145,728
  unsigned short* WoutT = (unsigned short*)(ws + 3145728);    //    131,072
  unsigned short* x     = (unsigned short*)(ws + 3276800);    //  8,388,608
  unsigned short* hxch  = (unsigned short*)(ws + 11665408);   // 16,777,216
  unsigned int*   flags = (unsigned int*)(ws + 28442624);     //        512
  float*          em    = (float*)(ws + 3276800);             //  8,388,608 (alias x)

  build_wcat<<<384, 256, 0, stream>>>(Wi, Wh, WcatT);
  build_wout<<<16, 256, 0, stream>>>(Wout, WoutT);
  embed_kernel<<<T_LEN * BB, 256, 0, stream>>>(wx, cx, we, ce, x);
  zero_flags<<<1, 128, 0, stream>>>(flags);
  lstm_persistent<<<64, 128, 0, stream>>>(x, hxch, WcatT, bias, wx, flags);
  em_gemm<<<256, 512, 0, stream>>>(hxch, WoutT, bout, wx, em);
  crf_kernel<<<BB, 512, 0, stream>>>(em, trans, wx, y, out);
}

// Round 12
// 1735.941 us; speedup vs baseline: 1.0268x; 1.0268x over previous
//
#include <hip/hip_runtime.h>

// ---------------------------------------------------------------------------
// RNN (LSTM) + CRF loss on MI355X — round 12.
// = round 10 (best, 1739us) with ONE change: exchange-path cache flags
// dropped from sc0 sc1 (SYSTEM scope) to sc1 (AGENT scope). LLC is the
// agent coherence point — sufficient for cross-XCD h/flag exchange; system
// scope was paying full-fabric round trips on the serial chain.
// LSTM: 64 blocks x 128 thr, 32x32x16 swapped MFMA, 192-VGPR resident
// weights, flag handshake (h store -> vmcnt ack -> syncthreads -> flag).
// CRF: E-precompute version. em_gemm: 256x512 (r10-proven).
// ---------------------------------------------------------------------------

typedef float f32x4 __attribute__((ext_vector_type(4)));
typedef float f32x16 __attribute__((ext_vector_type(16)));
typedef __bf16 bf16x8 __attribute__((ext_vector_type(8)));
typedef unsigned int u32x4 __attribute__((ext_vector_type(4)));
typedef unsigned int u32x2 __attribute__((ext_vector_type(2)));

#define T_LEN 256
#define BB    64
#define EE    256
#define HH    512
#define KK    128
#define KCAT  768   // E + H

static __device__ inline unsigned f2bf(float f) {
  union { float f; unsigned u; } v; v.f = f;
  unsigned r = v.u + 0x7FFF + ((v.u >> 16) & 1);   // round-nearest-even
  return r >> 16;
}
static __device__ inline float sigm(float x) { return 1.f / (1.f + __expf(-x)); }
static __device__ inline float tanh_fast(float x) {
  return 1.f - 2.f / (1.f + __expf(2.f * x));      // safe at +/-inf
}
static __device__ inline bf16x8 ubf(u32x4 v) {
  union { u32x4 u; bf16x8 b; } c; c.u = v; return c.b;
}

// --- 1. weight conversion (LDS tile transpose, coalesced both sides) -------
__global__ __launch_bounds__(256) void build_wcat(
    const float* __restrict__ Wi, const float* __restrict__ Wh,
    unsigned short* __restrict__ WcatT) {
  __shared__ float tile[64][65];
  int ct = blockIdx.x & 31, kt = blockIdx.x >> 5;    // 32 c-tiles x 12 k-tiles
  int tc = threadIdx.x & 63, tr = threadIdx.x >> 6;
  int c0 = ct * 64, k0 = kt * 64;
#pragma unroll
  for (int i = 0; i < 16; ++i) {
    int r = tr * 16 + i, k = k0 + r;
    float v = (k < EE) ? Wi[(size_t)k * 2048 + c0 + tc]
                       : Wh[(size_t)(k - EE) * 2048 + c0 + tc];
    tile[r][tc] = v;
  }
  __syncthreads();
#pragma unroll
  for (int i = 0; i < 16; ++i) {
    int cL = tr * 16 + i;
    WcatT[(size_t)(c0 + cL) * KCAT + k0 + tc] = (unsigned short)f2bf(tile[tc][cL]);
  }
}

__global__ __launch_bounds__(256) void build_wout(
    const float* __restrict__ Wout, unsigned short* __restrict__ WoutT) {
  __shared__ float tile[64][65];
  int ct = blockIdx.x & 1, kt = blockIdx.x >> 1;     // 2 c-tiles x 8 k-tiles
  int tc = threadIdx.x & 63, tr = threadIdx.x >> 6;
  int c0 = ct * 64, k0 = kt * 64;
#pragma unroll
  for (int i = 0; i < 16; ++i) {
    int r = tr * 16 + i;
    tile[r][tc] = Wout[(size_t)(k0 + r) * KK + c0 + tc];
  }
  __syncthreads();
#pragma unroll
  for (int i = 0; i < 16; ++i) {
    int cL = tr * 16 + i;
    WoutT[(size_t)(c0 + cL) * HH + k0 + tc] = (unsigned short)f2bf(tile[tc][cL]);
  }
}

// --- 2. embedding ----------------------------------------------------------
__global__ __launch_bounds__(256) void embed_kernel(
    const int* __restrict__ wx, const int* __restrict__ cx,
    const float* __restrict__ we, const float* __restrict__ ce,
    unsigned short* __restrict__ x) {
  int bid = blockIdx.x;             // t*64 + b
  int t = bid >> 6, b = bid & 63;
  int e = threadIdx.x;              // 0..255
  int w = wx[b * T_LEN + t];
  float v = we[(size_t)w * EE + e];
  const int* cp = cx + ((size_t)(b * T_LEN + t)) * 8;
  float s = 0.f;
#pragma unroll
  for (int l = 0; l < 8; ++l) s += ce[(size_t)cp[l] * EE + e];
  v += s * 0.125f;
  x[(size_t)bid * EE + e] = (unsigned short)f2bf(v);
}

// --- 3. flag reset (sc1 = agent scope: visible at LLC to all XCDs) ---------
__global__ void zero_flags(unsigned int* __restrict__ f) {
  unsigned z = 0u;
  asm volatile("global_store_dword %0, %1, off sc1"
               :: "v"(f + threadIdx.x), "v"(z) : "memory");
}

// --- 4. persistent LSTM (r10 structure; agent-scope exchange) ---------------
#define SBAR __builtin_amdgcn_sched_barrier(0)
#define WAITV(N) do { asm volatile("s_waitcnt vmcnt(" #N ")" ::: "memory"); SBAR; } while (0)
#define LDC(dst, ptr, OFF) \
  asm volatile("global_load_dwordx4 %0, %1, off offset:" OFF " sc1" \
               : "=v"(dst) : "v"(ptr) : "memory")
#define LDN(dst, ptr, OFF) \
  asm volatile("global_load_dwordx4 %0, %1, off offset:" OFF \
               : "=v"(dst) : "v"(ptr) : "memory")

#define ISSUE_X(B, P) do { \
  LDN(B[0],P,"0");   LDN(B[1],P,"32");  LDN(B[2],P,"64");  LDN(B[3],P,"96"); \
  LDN(B[4],P,"128"); LDN(B[5],P,"160"); LDN(B[6],P,"192"); LDN(B[7],P,"224"); \
  LDN(B[8],P,"256"); LDN(B[9],P,"288"); LDN(B[10],P,"320"); LDN(B[11],P,"352"); \
  LDN(B[12],P,"384"); LDN(B[13],P,"416"); LDN(B[14],P,"448"); LDN(B[15],P,"480"); } while (0)
#define ISSUE_H0(B, P) do { \
  LDC(B[0],P,"0");   LDC(B[1],P,"32");  LDC(B[2],P,"64");  LDC(B[3],P,"96"); \
  LDC(B[4],P,"128"); LDC(B[5],P,"160"); LDC(B[6],P,"192"); LDC(B[7],P,"224"); \
  LDC(B[8],P,"256"); LDC(B[9],P,"288"); LDC(B[10],P,"320"); LDC(B[11],P,"352"); \
  LDC(B[12],P,"384"); LDC(B[13],P,"416"); LDC(B[14],P,"448"); LDC(B[15],P,"480"); } while (0)
#define ISSUE_H1(B, P) do { \
  LDC(B[0],P,"512"); LDC(B[1],P,"544"); LDC(B[2],P,"576"); LDC(B[3],P,"608"); \
  LDC(B[4],P,"640"); LDC(B[5],P,"672"); LDC(B[6],P,"704"); LDC(B[7],P,"736"); \
  LDC(B[8],P,"768"); LDC(B[9],P,"800"); LDC(B[10],P,"832"); LDC(B[11],P,"864"); \
  LDC(B[12],P,"896"); LDC(B[13],P,"928"); LDC(B[14],P,"960"); LDC(B[15],P,"992"); } while (0)

#define GATES_STORE(T) do { \
    bool mk = ((int)wxv) > 0; \
    _Pragma("unroll") \
    for (int r = 0; r < 4; ++r) { \
      float zi = acc[r], zf = acc[4 + r], zg = acc[8 + r], zo = acc[12 + r]; \
      float cn = sigm(zf) * cst[r] + sigm(zi) * tanh_fast(zg); \
      float hn = sigm(zo) * tanh_fast(cn); \
      if (mk) { cst[r] = cn; hst[r] = hn; } \
    } \
    u32x2 ph; \
    ph[0] = f2bf(hst[0]) | (f2bf(hst[1]) << 16); \
    ph[1] = f2bf(hst[2]) | (f2bf(hst[3]) << 16); \
    asm volatile("global_store_dwordx2 %0, %1, off sc1" \
                 :: "v"(hstore + (size_t)(T) * 65536), "v"(ph) : "memory"); \
  } while (0)

// wave = 32 batches x 32 z-cols (32x32x16 swapped MFMA, D = Wfrag x Hfrag).
// D: col = lane&31 (batch), row = (reg&3) + 8*(reg>>2) + 4*(lane>>5)
//    = gate*8 + uoff  -> acc[g*4+r] = gate g, u = u0 + 4*hi + r. All 4 gates
// in-lane; weight A-frags (rows = z-cols) loop-invariant in 192 VGPRs.
__global__ __launch_bounds__(128, 1) void lstm_persistent(
    const unsigned short* __restrict__ x,      // [T][64][256] bf16
    unsigned short* __restrict__ hs,           // [256][64][512] bf16 (slot t = h[t+1])
    const unsigned short* __restrict__ WcatT,  // [2048][768] bf16
    const float* __restrict__ bias,            // [2048]
    const int* __restrict__ wx,                // [64][256]
    unsigned int* __restrict__ flags) {        // 64 packed dwords
  const int tid = threadIdx.x;
  const int lane = tid & 63;
  const int bhalf = tid >> 6;                  // 2 waves: batch halves
  const int hi = lane >> 5;
  const int batch = bhalf * 32 + (lane & 31);
  const int u0 = blockIdx.x * 8;               // block's u-slice [u0, u0+8)
  const int rr = lane & 31;                    // A-frag row = z-col id
  const int wcol = (rr >> 3) * HH + u0 + (rr & 7);   // gate*512 + u0 + uoff

  // 48 loop-invariant weight A-frags -> 192 VGPRs
  bf16x8 wreg[48];
#pragma unroll
  for (int kf = 0; kf < 48; ++kf)
    wreg[kf] = *(const bf16x8*)(WcatT + (size_t)wcol * KCAT + kf * 16 + hi * 8);

  float bv[16];
#pragma unroll
  for (int q = 0; q < 4; ++q)
#pragma unroll
    for (int r = 0; r < 4; ++r)
      bv[q * 4 + r] = bias[q * HH + u0 + 4 * hi + r];

  const char* xlane  = (const char*)x  + ((size_t)batch * EE + hi * 8) * 2;
  const char* hread  = (const char*)hs + ((size_t)batch * HH + hi * 8) * 2;
  char*       hstore = (char*)hs + ((size_t)batch * HH + u0 + 4 * hi) * 2;
  const int*  wxp    = wx + batch * T_LEN;

  float cst[4] = {0.f, 0.f, 0.f, 0.f};
  float hst[4] = {0.f, 0.f, 0.f, 0.f};
  u32x4 bufX[16], bufH[16];
  unsigned wxv;
  f32x16 acc;

  // ---- t = 0 (h = 0: x-part only) ----
  ISSUE_X(bufX, xlane);
  asm volatile("global_load_dword %0, %1, off" : "=v"(wxv) : "v"(wxp) : "memory");
  WAITV(0);
#pragma unroll
  for (int i = 0; i < 16; ++i) acc[i] = bv[i];
#pragma unroll
  for (int kf = 0; kf < 16; ++kf)
    acc = __builtin_amdgcn_mfma_f32_32x32x16_bf16(wreg[kf], ubf(bufX[kf]), acc, 0, 0, 0);
  GATES_STORE(0);
  WAITV(0);                                    // h[1] ack'd at LLC
  __syncthreads();
  if (tid == 0)
    __hip_atomic_store(flags + blockIdx.x, 1u, __ATOMIC_RELAXED, __HIP_MEMORY_SCOPE_AGENT);

  // ---- t = 1..255 ----
  for (int t = 1; t < T_LEN; ++t) {
    const char* xt = xlane + (size_t)t * 32768;
    const char* hp = hread + (size_t)(t - 1) * 65536;

    ISSUE_X(bufX, xt);
    asm volatile("global_load_dword %0, %1, off" : "=v"(wxv) : "v"(wxp + t) : "memory");
    // poll 64 packed producer flags: one coalesced dword per lane (agent scope)
    {
      unsigned v;
      do {
        asm volatile("global_load_dword %0, %1, off sc1\n\ts_waitcnt vmcnt(0)"
                     : "=v"(v) : "v"(flags + lane) : "memory");
      } while (!__all((int)(v >= (unsigned)t)));
      SBAR;
    }
    ISSUE_H0(bufH, hp);                        // h chunk 0 in flight
#pragma unroll
    for (int i = 0; i < 16; ++i) acc[i] = bv[i];
#pragma unroll
    for (int kf = 0; kf < 16; ++kf)            // x-part (data arrived: poll drained)
      acc = __builtin_amdgcn_mfma_f32_32x32x16_bf16(wreg[kf], ubf(bufX[kf]), acc, 0, 0, 0);
    SBAR;
    ISSUE_H1(bufX, hp);                        // h chunk 1 reuses x buffer
    WAITV(16);                                 // chunk 0 arrived
#pragma unroll
    for (int kf = 0; kf < 16; ++kf)
      acc = __builtin_amdgcn_mfma_f32_32x32x16_bf16(wreg[16 + kf], ubf(bufH[kf]), acc, 0, 0, 0);
    WAITV(0);                                  // chunk 1 arrived
#pragma unroll
    for (int kf = 0; kf < 16; ++kf)
      acc = __builtin_amdgcn_mfma_f32_32x32x16_bf16(wreg[32 + kf], ubf(bufX[kf]), acc, 0, 0, 0);
    GATES_STORE(t);
    WAITV(0);                                  // h[t+1] ack'd at LLC
    __syncthreads();                           // both waves drained
    if (tid == 0)
      __hip_atomic_store(flags + blockIdx.x, (unsigned)(t + 1),
                         __ATOMIC_RELAXED, __HIP_MEMORY_SCOPE_AGENT);
  }
}

// --- 5. emissions GEMM: 256 blocks x 512 thr, 64 rows x 128 cols/block -----
__global__ __launch_bounds__(512) void em_gemm(
    const unsigned short* __restrict__ hs,    // [256][64][512] bf16
    const unsigned short* __restrict__ WoutT, // [128][512] bf16
    const float* __restrict__ bout,
    const int* __restrict__ wx,
    float* __restrict__ em) {                 // [16384][128]
  int mg = blockIdx.x;                        // 0..255
  int wave = threadIdx.x >> 6, lane = threadIdx.x & 63;
  int m = wave >> 1, nh = wave & 1;
  int arow = lane & 15, kg = (lane >> 4) * 8;
  int rbase = mg * 64 + m * 16;
  const unsigned short* A = hs + (size_t)(rbase + arow) * HH + kg;
  f32x4 acc[4];
#pragma unroll
  for (int nt = 0; nt < 4; ++nt) acc[nt] = (f32x4){0.f, 0.f, 0.f, 0.f};
#pragma unroll
  for (int ks = 0; ks < 16; ++ks) {
    bf16x8 a = *(const bf16x8*)(A + ks * 32);
#pragma unroll
    for (int nt = 0; nt < 4; ++nt) {
      const unsigned short* Bp =
          WoutT + (size_t)(nh * 64 + nt * 16 + arow) * HH + kg + ks * 32;
      acc[nt] = __builtin_amdgcn_mfma_f32_16x16x32_bf16(a, *(const bf16x8*)Bp, acc[nt], 0, 0, 0);
    }
  }
#pragma unroll
  for (int nt = 0; nt < 4; ++nt) {
    int n = nh * 64 + nt * 16 + arow;
    float bo = bout[n];
#pragma unroll
    for (int r = 0; r < 4; ++r) {
      int row = rbase + (lane >> 4) * 4 + r;  // t*64 + b
      int t = row >> 6, b = row & 63;
      float v = (acc[nt][r] + bo) * ((wx[b * T_LEN + t] > 0) ? 1.f : 0.f);
      em[(size_t)row * KK + n] = v;
    }
  }
}

// --- 6. CRF forward + gold — E-precompute version (r10, proven) -------------
__global__ __launch_bounds__(512) void crf_kernel(
    const float* __restrict__ em,             // [256][64][128]
    const float* __restrict__ trans,          // [128][128]
    const int* __restrict__ wx,
    const int* __restrict__ y,                // [64][257]
    float* __restrict__ out) {
  int b = blockIdx.x;
  __shared__ float tl[KK][129];
  __shared__ float El[KK][129];
  __shared__ float sc[KK];
  __shared__ float p[KK];
  __shared__ float red[512];
  __shared__ float red2[512];
  __shared__ float mshare[2];
  int tid = threadIdx.x;
  for (int i = tid; i < KK * KK; i += 512) {
    float v = trans[i];
    tl[i >> 7][i & 127] = v;
    El[i >> 7][i & 127] = __expf(v);          // exp(-1e4) = 0
  }
  if (tid < KK) sc[tid] = (tid == 1) ? 0.f : -10000.f;
  __syncthreads();

  int k = tid & 127, q = tid >> 7, j0 = q * 32;
  float msc = 0.f;                             // max_k sc (k=SOS is 0)

  for (int t = 0; t < T_LEN; ++t) {
    if (wx[b * T_LEN + t] <= 0) continue;      // block-uniform
    if (tid < KK) p[tid] = __expf(sc[tid] - msc);
    __syncthreads();
    float S = 0.f;
#pragma unroll
    for (int j = 0; j < 32; ++j) S += El[k][j0 + j] * p[j0 + j];
    red[tid] = S;
    __syncthreads();
    if (q == 0) {                              // waves 0,1: k = 0..127
      float Sk = S + red[128 + k] + red[256 + k] + red[384 + k];
      float ns = em[(size_t)(t * BB + b) * KK + k] + msc + __logf(Sk);
      sc[k] = ns;
      float m = ns;                            // wave max over 64 lanes
#pragma unroll
      for (int off = 32; off; off >>= 1) m = fmaxf(m, __shfl_xor(m, off));
      if ((tid & 63) == 0) mshare[tid >> 6] = m;
    }
    __syncthreads();
    msc = fmaxf(mshare[0], mshare[1]);
  }

  // gold score
  float term = 0.f, cnt = 0.f;
  if (tid < T_LEN) {
    int yp = y[b * 257 + tid], yn = y[b * 257 + tid + 1];
    if (wx[b * T_LEN + tid] > 0) {
      term = em[(size_t)(tid * BB + b) * KK + yn] + tl[yn][yp];
      cnt = 1.f;
    }
  }
  red[tid] = term; red2[tid] = cnt;
  __syncthreads();
  for (int s2 = 256; s2 > 0; s2 >>= 1) {
    if (tid < s2) { red[tid] += red[tid + s2]; red2[tid] += red2[tid + s2]; }
    __syncthreads();
  }
  float gold = red[0];
  int len = (int)(red2[0] + 0.5f);
  __syncthreads();

  // Z = LSE_k(sc[k] + trans[EOS][k])
  float v = (tid < KK) ? sc[tid] + tl[2][tid] : -3.0e38f;
  red[tid] = v;
  __syncthreads();
  for (int s2 = 256; s2 > 0; s2 >>= 1) {
    if (tid < s2) red[tid] = fmaxf(red[tid], red[tid + s2]);
    __syncthreads();
  }
  float mz = red[0];
  __syncthreads();
  red[tid] = (tid < KK) ? __expf(v - mz) : 0.f;
  __syncthreads();
  for (int s2 = 256; s2 > 0; s2 >>= 1) {
    if (tid < s2) red[tid] += red[tid + s2];
    __syncthreads();
  }
  if (tid == 0) {
    float Z = mz + __logf(red[0]);
    int last_tag = y[b * 257 + len];
    out[b] = Z - (gold + tl[2][last_tag]);
  }
}

// ---------------------------------------------------------------------------
extern "C" void kernel_launch(void* const* d_in, const int* in_sizes, int n_in,
                              void* d_out, int out_size, void* d_ws, size_t ws_size,
                              hipStream_t stream) {
  const int*   cx    = (const int*)d_in[0];
  const int*   wx    = (const int*)d_in[1];
  const int*   y     = (const int*)d_in[2];
  const float* ce    = (const float*)d_in[3];
  const float* we    = (const float*)d_in[4];
  const float* Wi    = (const float*)d_in[5];
  const float* Wh    = (const float*)d_in[6];
  const float* bias  = (const float*)d_in[7];
  const float* Wout  = (const float*)d_in[8];
  const float* bout  = (const float*)d_in[9];
  const float* trans = (const float*)d_in[10];
  float* out = (float*)d_out;

  char* ws = (char*)d_ws;
  // ws layout (16B aligned), ~28.5 MB; em aliases x (x dead after lstm)
  unsigned short* WcatT = (unsigned short*)(ws + 0);          //  3,145,728
  unsigned short* WoutT = (unsigned short*)(ws + 3145728);    //    131,072
  unsigned short* x     = (unsigned short*)(ws + 3276800);    //  8,388,608
  unsigned short* hs    = (unsigned short*)(ws + 11665408);   // 16,777,216
  unsigned int*   flags = (unsigned int*)(ws + 28442624);     //        256
  float*          em    = (float*)(ws + 3276800);             //  8,388,608 (alias x)

  build_wcat<<<384, 256, 0, stream>>>(Wi, Wh, WcatT);
  build_wout<<<16, 256, 0, stream>>>(Wout, WoutT);
  embed_kernel<<<T_LEN * BB, 256, 0, stream>>>(wx, cx, we, ce, x);
  zero_flags<<<1, 64, 0, stream>>>(flags);
  lstm_persistent<<<64, 128, 0, stream>>>(x, hs, WcatT, bias, wx, flags);
  em_gemm<<<256, 512, 0, stream>>>(hs, WoutT, bout, wx, em);
  crf_kernel<<<BB, 512, 0, stream>>>(em, trans, wx, y, out);
}

// Round 13
// 1616.430 us; speedup vs baseline: 1.1028x; 1.0739x over previous
//
#include <hip/hip_runtime.h>

// ---------------------------------------------------------------------------
// RNN (LSTM) + CRF loss on MI355X — round 13.
// = round 12 with ONE change: h-data loads are PLAIN (L2-cacheable) instead
// of sc1. Each hs slot is write-once/read-once per dispatch and L2 is
// invalidated at dispatch boundaries (incl. graph replays — the r1
// multi-launch design relied on this), so plain loads are safe; same-XCD
// blocks now share h lines through their L2, cutting the per-step LLC
// fan-out 8x (65k -> 8k line-requests). Flags stay sc1 (change per step);
// h stores stay sc1 (write-through publish to LLC before the flag).
// ---------------------------------------------------------------------------

typedef float f32x4 __attribute__((ext_vector_type(4)));
typedef float f32x16 __attribute__((ext_vector_type(16)));
typedef __bf16 bf16x8 __attribute__((ext_vector_type(8)));
typedef unsigned int u32x4 __attribute__((ext_vector_type(4)));
typedef unsigned int u32x2 __attribute__((ext_vector_type(2)));

#define T_LEN 256
#define BB    64
#define EE    256
#define HH    512
#define KK    128
#define KCAT  768   // E + H

static __device__ inline unsigned f2bf(float f) {
  union { float f; unsigned u; } v; v.f = f;
  unsigned r = v.u + 0x7FFF + ((v.u >> 16) & 1);   // round-nearest-even
  return r >> 16;
}
static __device__ inline float sigm(float x) { return 1.f / (1.f + __expf(-x)); }
static __device__ inline float tanh_fast(float x) {
  return 1.f - 2.f / (1.f + __expf(2.f * x));      // safe at +/-inf
}
static __device__ inline bf16x8 ubf(u32x4 v) {
  union { u32x4 u; bf16x8 b; } c; c.u = v; return c.b;
}

// --- 1. weight conversion (LDS tile transpose, coalesced both sides) -------
__global__ __launch_bounds__(256) void build_wcat(
    const float* __restrict__ Wi, const float* __restrict__ Wh,
    unsigned short* __restrict__ WcatT) {
  __shared__ float tile[64][65];
  int ct = blockIdx.x & 31, kt = blockIdx.x >> 5;    // 32 c-tiles x 12 k-tiles
  int tc = threadIdx.x & 63, tr = threadIdx.x >> 6;
  int c0 = ct * 64, k0 = kt * 64;
#pragma unroll
  for (int i = 0; i < 16; ++i) {
    int r = tr * 16 + i, k = k0 + r;
    float v = (k < EE) ? Wi[(size_t)k * 2048 + c0 + tc]
                       : Wh[(size_t)(k - EE) * 2048 + c0 + tc];
    tile[r][tc] = v;
  }
  __syncthreads();
#pragma unroll
  for (int i = 0; i < 16; ++i) {
    int cL = tr * 16 + i;
    WcatT[(size_t)(c0 + cL) * KCAT + k0 + tc] = (unsigned short)f2bf(tile[tc][cL]);
  }
}

__global__ __launch_bounds__(256) void build_wout(
    const float* __restrict__ Wout, unsigned short* __restrict__ WoutT) {
  __shared__ float tile[64][65];
  int ct = blockIdx.x & 1, kt = blockIdx.x >> 1;     // 2 c-tiles x 8 k-tiles
  int tc = threadIdx.x & 63, tr = threadIdx.x >> 6;
  int c0 = ct * 64, k0 = kt * 64;
#pragma unroll
  for (int i = 0; i < 16; ++i) {
    int r = tr * 16 + i;
    tile[r][tc] = Wout[(size_t)(k0 + r) * KK + c0 + tc];
  }
  __syncthreads();
#pragma unroll
  for (int i = 0; i < 16; ++i) {
    int cL = tr * 16 + i;
    WoutT[(size_t)(c0 + cL) * HH + k0 + tc] = (unsigned short)f2bf(tile[tc][cL]);
  }
}

// --- 2. embedding ----------------------------------------------------------
__global__ __launch_bounds__(256) void embed_kernel(
    const int* __restrict__ wx, const int* __restrict__ cx,
    const float* __restrict__ we, const float* __restrict__ ce,
    unsigned short* __restrict__ x) {
  int bid = blockIdx.x;             // t*64 + b
  int t = bid >> 6, b = bid & 63;
  int e = threadIdx.x;              // 0..255
  int w = wx[b * T_LEN + t];
  float v = we[(size_t)w * EE + e];
  const int* cp = cx + ((size_t)(b * T_LEN + t)) * 8;
  float s = 0.f;
#pragma unroll
  for (int l = 0; l < 8; ++l) s += ce[(size_t)cp[l] * EE + e];
  v += s * 0.125f;
  x[(size_t)bid * EE + e] = (unsigned short)f2bf(v);
}

// --- 3. flag reset (sc1 = agent scope: visible at LLC to all XCDs) ---------
__global__ void zero_flags(unsigned int* __restrict__ f) {
  unsigned z = 0u;
  asm volatile("global_store_dword %0, %1, off sc1"
               :: "v"(f + threadIdx.x), "v"(z) : "memory");
}

// --- 4. persistent LSTM (r12 structure; plain h loads) ----------------------
#define SBAR __builtin_amdgcn_sched_barrier(0)
#define WAITV(N) do { asm volatile("s_waitcnt vmcnt(" #N ")" ::: "memory"); SBAR; } while (0)
#define LDN(dst, ptr, OFF) \
  asm volatile("global_load_dwordx4 %0, %1, off offset:" OFF \
               : "=v"(dst) : "v"(ptr) : "memory")

#define ISSUE_X(B, P) do { \
  LDN(B[0],P,"0");   LDN(B[1],P,"32");  LDN(B[2],P,"64");  LDN(B[3],P,"96"); \
  LDN(B[4],P,"128"); LDN(B[5],P,"160"); LDN(B[6],P,"192"); LDN(B[7],P,"224"); \
  LDN(B[8],P,"256"); LDN(B[9],P,"288"); LDN(B[10],P,"320"); LDN(B[11],P,"352"); \
  LDN(B[12],P,"384"); LDN(B[13],P,"416"); LDN(B[14],P,"448"); LDN(B[15],P,"480"); } while (0)
#define ISSUE_H0(B, P) do { \
  LDN(B[0],P,"0");   LDN(B[1],P,"32");  LDN(B[2],P,"64");  LDN(B[3],P,"96"); \
  LDN(B[4],P,"128"); LDN(B[5],P,"160"); LDN(B[6],P,"192"); LDN(B[7],P,"224"); \
  LDN(B[8],P,"256"); LDN(B[9],P,"288"); LDN(B[10],P,"320"); LDN(B[11],P,"352"); \
  LDN(B[12],P,"384"); LDN(B[13],P,"416"); LDN(B[14],P,"448"); LDN(B[15],P,"480"); } while (0)
#define ISSUE_H1(B, P) do { \
  LDN(B[0],P,"512"); LDN(B[1],P,"544"); LDN(B[2],P,"576"); LDN(B[3],P,"608"); \
  LDN(B[4],P,"640"); LDN(B[5],P,"672"); LDN(B[6],P,"704"); LDN(B[7],P,"736"); \
  LDN(B[8],P,"768"); LDN(B[9],P,"800"); LDN(B[10],P,"832"); LDN(B[11],P,"864"); \
  LDN(B[12],P,"896"); LDN(B[13],P,"928"); LDN(B[14],P,"960"); LDN(B[15],P,"992"); } while (0)

#define GATES_STORE(T) do { \
    bool mk = ((int)wxv) > 0; \
    _Pragma("unroll") \
    for (int r = 0; r < 4; ++r) { \
      float zi = acc[r], zf = acc[4 + r], zg = acc[8 + r], zo = acc[12 + r]; \
      float cn = sigm(zf) * cst[r] + sigm(zi) * tanh_fast(zg); \
      float hn = sigm(zo) * tanh_fast(cn); \
      if (mk) { cst[r] = cn; hst[r] = hn; } \
    } \
    u32x2 ph; \
    ph[0] = f2bf(hst[0]) | (f2bf(hst[1]) << 16); \
    ph[1] = f2bf(hst[2]) | (f2bf(hst[3]) << 16); \
    asm volatile("global_store_dwordx2 %0, %1, off sc1" \
                 :: "v"(hstore + (size_t)(T) * 65536), "v"(ph) : "memory"); \
  } while (0)

// wave = 32 batches x 32 z-cols (32x32x16 swapped MFMA, D = Wfrag x Hfrag).
// D: col = lane&31 (batch), row = (reg&3) + 8*(reg>>2) + 4*(lane>>5)
//    = gate*8 + uoff  -> acc[g*4+r] = gate g, u = u0 + 4*hi + r. All 4 gates
// in-lane; weight A-frags (rows = z-cols) loop-invariant in 192 VGPRs.
__global__ __launch_bounds__(128, 1) void lstm_persistent(
    const unsigned short* __restrict__ x,      // [T][64][256] bf16
    unsigned short* __restrict__ hs,           // [256][64][512] bf16 (slot t = h[t+1])
    const unsigned short* __restrict__ WcatT,  // [2048][768] bf16
    const float* __restrict__ bias,            // [2048]
    const int* __restrict__ wx,                // [64][256]
    unsigned int* __restrict__ flags) {        // 64 packed dwords
  const int tid = threadIdx.x;
  const int lane = tid & 63;
  const int bhalf = tid >> 6;                  // 2 waves: batch halves
  const int hi = lane >> 5;
  const int batch = bhalf * 32 + (lane & 31);
  const int u0 = blockIdx.x * 8;               // block's u-slice [u0, u0+8)
  const int rr = lane & 31;                    // A-frag row = z-col id
  const int wcol = (rr >> 3) * HH + u0 + (rr & 7);   // gate*512 + u0 + uoff

  // 48 loop-invariant weight A-frags -> 192 VGPRs
  bf16x8 wreg[48];
#pragma unroll
  for (int kf = 0; kf < 48; ++kf)
    wreg[kf] = *(const bf16x8*)(WcatT + (size_t)wcol * KCAT + kf * 16 + hi * 8);

  float bv[16];
#pragma unroll
  for (int q = 0; q < 4; ++q)
#pragma unroll
    for (int r = 0; r < 4; ++r)
      bv[q * 4 + r] = bias[q * HH + u0 + 4 * hi + r];

  const char* xlane  = (const char*)x  + ((size_t)batch * EE + hi * 8) * 2;
  const char* hread  = (const char*)hs + ((size_t)batch * HH + hi * 8) * 2;
  char*       hstore = (char*)hs + ((size_t)batch * HH + u0 + 4 * hi) * 2;
  const int*  wxp    = wx + batch * T_LEN;

  float cst[4] = {0.f, 0.f, 0.f, 0.f};
  float hst[4] = {0.f, 0.f, 0.f, 0.f};
  u32x4 bufX[16], bufH[16];
  unsigned wxv;
  f32x16 acc;

  // ---- t = 0 (h = 0: x-part only) ----
  ISSUE_X(bufX, xlane);
  asm volatile("global_load_dword %0, %1, off" : "=v"(wxv) : "v"(wxp) : "memory");
  WAITV(0);
#pragma unroll
  for (int i = 0; i < 16; ++i) acc[i] = bv[i];
#pragma unroll
  for (int kf = 0; kf < 16; ++kf)
    acc = __builtin_amdgcn_mfma_f32_32x32x16_bf16(wreg[kf], ubf(bufX[kf]), acc, 0, 0, 0);
  GATES_STORE(0);
  WAITV(0);                                    // h[1] ack'd at LLC
  __syncthreads();
  if (tid == 0)
    __hip_atomic_store(flags + blockIdx.x, 1u, __ATOMIC_RELAXED, __HIP_MEMORY_SCOPE_AGENT);

  // ---- t = 1..255 ----
  for (int t = 1; t < T_LEN; ++t) {
    const char* xt = xlane + (size_t)t * 32768;
    const char* hp = hread + (size_t)(t - 1) * 65536;

    ISSUE_X(bufX, xt);
    asm volatile("global_load_dword %0, %1, off" : "=v"(wxv) : "v"(wxp + t) : "memory");
    // poll 64 packed producer flags: one coalesced dword per lane (agent scope)
    {
      unsigned v;
      do {
        asm volatile("global_load_dword %0, %1, off sc1\n\ts_waitcnt vmcnt(0)"
                     : "=v"(v) : "v"(flags + lane) : "memory");
      } while (!__all((int)(v >= (unsigned)t)));
      SBAR;
    }
    ISSUE_H0(bufH, hp);                        // h chunk 0 in flight (plain, L2-shared)
#pragma unroll
    for (int i = 0; i < 16; ++i) acc[i] = bv[i];
#pragma unroll
    for (int kf = 0; kf < 16; ++kf)            // x-part (data arrived: poll drained)
      acc = __builtin_amdgcn_mfma_f32_32x32x16_bf16(wreg[kf], ubf(bufX[kf]), acc, 0, 0, 0);
    SBAR;
    ISSUE_H1(bufX, hp);                        // h chunk 1 reuses x buffer
    WAITV(16);                                 // chunk 0 arrived
#pragma unroll
    for (int kf = 0; kf < 16; ++kf)
      acc = __builtin_amdgcn_mfma_f32_32x32x16_bf16(wreg[16 + kf], ubf(bufH[kf]), acc, 0, 0, 0);
    WAITV(0);                                  // chunk 1 arrived
#pragma unroll
    for (int kf = 0; kf < 16; ++kf)
      acc = __builtin_amdgcn_mfma_f32_32x32x16_bf16(wreg[32 + kf], ubf(bufX[kf]), acc, 0, 0, 0);
    GATES_STORE(t);
    WAITV(0);                                  // h[t+1] ack'd at LLC
    __syncthreads();                           // both waves drained
    if (tid == 0)
      __hip_atomic_store(flags + blockIdx.x, (unsigned)(t + 1),
                         __ATOMIC_RELAXED, __HIP_MEMORY_SCOPE_AGENT);
  }
}

// --- 5. emissions GEMM: 256 blocks x 512 thr, 64 rows x 128 cols/block -----
__global__ __launch_bounds__(512) void em_gemm(
    const unsigned short* __restrict__ hs,    // [256][64][512] bf16
    const unsigned short* __restrict__ WoutT, // [128][512] bf16
    const float* __restrict__ bout,
    const int* __restrict__ wx,
    float* __restrict__ em) {                 // [16384][128]
  int mg = blockIdx.x;                        // 0..255
  int wave = threadIdx.x >> 6, lane = threadIdx.x & 63;
  int m = wave >> 1, nh = wave & 1;
  int arow = lane & 15, kg = (lane >> 4) * 8;
  int rbase = mg * 64 + m * 16;
  const unsigned short* A = hs + (size_t)(rbase + arow) * HH + kg;
  f32x4 acc[4];
#pragma unroll
  for (int nt = 0; nt < 4; ++nt) acc[nt] = (f32x4){0.f, 0.f, 0.f, 0.f};
#pragma unroll
  for (int ks = 0; ks < 16; ++ks) {
    bf16x8 a = *(const bf16x8*)(A + ks * 32);
#pragma unroll
    for (int nt = 0; nt < 4; ++nt) {
      const unsigned short* Bp =
          WoutT + (size_t)(nh * 64 + nt * 16 + arow) * HH + kg + ks * 32;
      acc[nt] = __builtin_amdgcn_mfma_f32_16x16x32_bf16(a, *(const bf16x8*)Bp, acc[nt], 0, 0, 0);
    }
  }
#pragma unroll
  for (int nt = 0; nt < 4; ++nt) {
    int n = nh * 64 + nt * 16 + arow;
    float bo = bout[n];
#pragma unroll
    for (int r = 0; r < 4; ++r) {
      int row = rbase + (lane >> 4) * 4 + r;  // t*64 + b
      int t = row >> 6, b = row & 63;
      float v = (acc[nt][r] + bo) * ((wx[b * T_LEN + t] > 0) ? 1.f : 0.f);
      em[(size_t)row * KK + n] = v;
    }
  }
}

// --- 6. CRF forward + gold — E-precompute version (r10, proven) -------------
__global__ __launch_bounds__(512) void crf_kernel(
    const float* __restrict__ em,             // [256][64][128]
    const float* __restrict__ trans,          // [128][128]
    const int* __restrict__ wx,
    const int* __restrict__ y,                // [64][257]
    float* __restrict__ out) {
  int b = blockIdx.x;
  __shared__ float tl[KK][129];
  __shared__ float El[KK][129];
  __shared__ float sc[KK];
  __shared__ float p[KK];
  __shared__ float red[512];
  __shared__ float red2[512];
  __shared__ float mshare[2];
  int tid = threadIdx.x;
  for (int i = tid; i < KK * KK; i += 512) {
    float v = trans[i];
    tl[i >> 7][i & 127] = v;
    El[i >> 7][i & 127] = __expf(v);          // exp(-1e4) = 0
  }
  if (tid < KK) sc[tid] = (tid == 1) ? 0.f : -10000.f;
  __syncthreads();

  int k = tid & 127, q = tid >> 7, j0 = q * 32;
  float msc = 0.f;                             // max_k sc (k=SOS is 0)

  for (int t = 0; t < T_LEN; ++t) {
    if (wx[b * T_LEN + t] <= 0) continue;      // block-uniform
    if (tid < KK) p[tid] = __expf(sc[tid] - msc);
    __syncthreads();
    float S = 0.f;
#pragma unroll
    for (int j = 0; j < 32; ++j) S += El[k][j0 + j] * p[j0 + j];
    red[tid] = S;
    __syncthreads();
    if (q == 0) {                              // waves 0,1: k = 0..127
      float Sk = S + red[128 + k] + red[256 + k] + red[384 + k];
      float ns = em[(size_t)(t * BB + b) * KK + k] + msc + __logf(Sk);
      sc[k] = ns;
      float m = ns;                            // wave max over 64 lanes
#pragma unroll
      for (int off = 32; off; off >>= 1) m = fmaxf(m, __shfl_xor(m, off));
      if ((tid & 63) == 0) mshare[tid >> 6] = m;
    }
    __syncthreads();
    msc = fmaxf(mshare[0], mshare[1]);
  }

  // gold score
  float term = 0.f, cnt = 0.f;
  if (tid < T_LEN) {
    int yp = y[b * 257 + tid], yn = y[b * 257 + tid + 1];
    if (wx[b * T_LEN + tid] > 0) {
      term = em[(size_t)(tid * BB + b) * KK + yn] + tl[yn][yp];
      cnt = 1.f;
    }
  }
  red[tid] = term; red2[tid] = cnt;
  __syncthreads();
  for (int s2 = 256; s2 > 0; s2 >>= 1) {
    if (tid < s2) { red[tid] += red[tid + s2]; red2[tid] += red2[tid + s2]; }
    __syncthreads();
  }
  float gold = red[0];
  int len = (int)(red2[0] + 0.5f);
  __syncthreads();

  // Z = LSE_k(sc[k] + trans[EOS][k])
  float v = (tid < KK) ? sc[tid] + tl[2][tid] : -3.0e38f;
  red[tid] = v;
  __syncthreads();
  for (int s2 = 256; s2 > 0; s2 >>= 1) {
    if (tid < s2) red[tid] = fmaxf(red[tid], red[tid + s2]);
    __syncthreads();
  }
  float mz = red[0];
  __syncthreads();
  red[tid] = (tid < KK) ? __expf(v - mz) : 0.f;
  __syncthreads();
  for (int s2 = 256; s2 > 0; s2 >>= 1) {
    if (tid < s2) red[tid] += red[tid + s2];
    __syncthreads();
  }
  if (tid == 0) {
    float Z = mz + __logf(red[0]);
    int last_tag = y[b * 257 + len];
    out[b] = Z - (gold + tl[2][last_tag]);
  }
}

// ---------------------------------------------------------------------------
extern "C" void kernel_launch(void* const* d_in, const int* in_sizes, int n_in,
                              void* d_out, int out_size, void* d_ws, size_t ws_size,
                              hipStream_t stream) {
  const int*   cx    = (const int*)d_in[0];
  const int*   wx    = (const int*)d_in[1];
  const int*   y     = (const int*)d_in[2];
  const float* ce    = (const float*)d_in[3];
  const float* we    = (const float*)d_in[4];
  const float* Wi    = (const float*)d_in[5];
  const float* Wh    = (const float*)d_in[6];
  const float* bias  = (const float*)d_in[7];
  const float* Wout  = (const float*)d_in[8];
  const float* bout  = (const float*)d_in[9];
  const float* trans = (const float*)d_in[10];
  float* out = (float*)d_out;

  char* ws = (char*)d_ws;
  // ws layout (16B aligned), ~28.5 MB; em aliases x (x dead after lstm)
  unsigned short* WcatT = (unsigned short*)(ws + 0);          //  3,145,728
  unsigned short* WoutT = (unsigned short*)(ws + 3145728);    //    131,072
  unsigned short* x     = (unsigned short*)(ws + 3276800);    //  8,388,608
  unsigned short* hs    = (unsigned short*)(ws + 11665408);   // 16,777,216
  unsigned int*   flags = (unsigned int*)(ws + 28442624);     //        256
  float*          em    = (float*)(ws + 3276800);             //  8,388,608 (alias x)

  build_wcat<<<384, 256, 0, stream>>>(Wi, Wh, WcatT);
  build_wout<<<16, 256, 0, stream>>>(Wout, WoutT);
  embed_kernel<<<T_LEN * BB, 256, 0, stream>>>(wx, cx, we, ce, x);
  zero_flags<<<1, 64, 0, stream>>>(flags);
  lstm_persistent<<<64, 128, 0, stream>>>(x, hs, WcatT, bias, wx, flags);
  em_gemm<<<256, 512, 0, stream>>>(hs, WoutT, bout, wx, em);
  crf_kernel<<<BB, 512, 0, stream>>>(em, trans, wx, y, out);
}

// Round 14
// 1463.474 us; speedup vs baseline: 1.2180x; 1.1045x over previous
//
#include <hip/hip_runtime.h>

// ---------------------------------------------------------------------------
// RNN (LSTM) + CRF loss on MI355X — round 14.
// Fused persistent launch: 136 blocks x 128 thr.
//   bid 0-63 : LSTM (r13 VERBATIM: plain h loads, sc1 stores, flag handshake)
//   bid 64-71: em producers (poll lstm flags -> em[t] via 16x16x32 -> emflag)
//   bid 72-135: CRF per-batch (poll emflag[t] -> E-precompute step)
// CRF/em chains now overlap the LSTM chain instead of trailing it.
// ---------------------------------------------------------------------------

typedef float f32x4 __attribute__((ext_vector_type(4)));
typedef float f32x16 __attribute__((ext_vector_type(16)));
typedef __bf16 bf16x8 __attribute__((ext_vector_type(8)));
typedef unsigned int u32x4 __attribute__((ext_vector_type(4)));
typedef unsigned int u32x2 __attribute__((ext_vector_type(2)));

#define T_LEN 256
#define BB    64
#define EE    256
#define HH    512
#define KK    128
#define KCAT  768   // E + H

static __device__ inline unsigned f2bf(float f) {
  union { float f; unsigned u; } v; v.f = f;
  unsigned r = v.u + 0x7FFF + ((v.u >> 16) & 1);   // round-nearest-even
  return r >> 16;
}
static __device__ inline float sigm(float x) { return 1.f / (1.f + __expf(-x)); }
static __device__ inline float tanh_fast(float x) {
  return 1.f - 2.f / (1.f + __expf(2.f * x));      // safe at +/-inf
}
static __device__ inline bf16x8 ubf(u32x4 v) {
  union { u32x4 u; bf16x8 b; } c; c.u = v; return c.b;
}

// --- 1. weight conversion (LDS tile transpose, coalesced both sides) -------
__global__ __launch_bounds__(256) void build_wcat(
    const float* __restrict__ Wi, const float* __restrict__ Wh,
    unsigned short* __restrict__ WcatT) {
  __shared__ float tile[64][65];
  int ct = blockIdx.x & 31, kt = blockIdx.x >> 5;    // 32 c-tiles x 12 k-tiles
  int tc = threadIdx.x & 63, tr = threadIdx.x >> 6;
  int c0 = ct * 64, k0 = kt * 64;
#pragma unroll
  for (int i = 0; i < 16; ++i) {
    int r = tr * 16 + i, k = k0 + r;
    float v = (k < EE) ? Wi[(size_t)k * 2048 + c0 + tc]
                       : Wh[(size_t)(k - EE) * 2048 + c0 + tc];
    tile[r][tc] = v;
  }
  __syncthreads();
#pragma unroll
  for (int i = 0; i < 16; ++i) {
    int cL = tr * 16 + i;
    WcatT[(size_t)(c0 + cL) * KCAT + k0 + tc] = (unsigned short)f2bf(tile[tc][cL]);
  }
}

__global__ __launch_bounds__(256) void build_wout(
    const float* __restrict__ Wout, unsigned short* __restrict__ WoutT) {
  __shared__ float tile[64][65];
  int ct = blockIdx.x & 1, kt = blockIdx.x >> 1;     // 2 c-tiles x 8 k-tiles
  int tc = threadIdx.x & 63, tr = threadIdx.x >> 6;
  int c0 = ct * 64, k0 = kt * 64;
#pragma unroll
  for (int i = 0; i < 16; ++i) {
    int r = tr * 16 + i;
    tile[r][tc] = Wout[(size_t)(k0 + r) * KK + c0 + tc];
  }
  __syncthreads();
#pragma unroll
  for (int i = 0; i < 16; ++i) {
    int cL = tr * 16 + i;
    WoutT[(size_t)(c0 + cL) * HH + k0 + tc] = (unsigned short)f2bf(tile[tc][cL]);
  }
}

// --- 2. embedding ----------------------------------------------------------
__global__ __launch_bounds__(256) void embed_kernel(
    const int* __restrict__ wx, const int* __restrict__ cx,
    const float* __restrict__ we, const float* __restrict__ ce,
    unsigned short* __restrict__ x) {
  int bid = blockIdx.x;             // t*64 + b
  int t = bid >> 6, b = bid & 63;
  int e = threadIdx.x;              // 0..255
  int w = wx[b * T_LEN + t];
  float v = we[(size_t)w * EE + e];
  const int* cp = cx + ((size_t)(b * T_LEN + t)) * 8;
  float s = 0.f;
#pragma unroll
  for (int l = 0; l < 8; ++l) s += ce[(size_t)cp[l] * EE + e];
  v += s * 0.125f;
  x[(size_t)bid * EE + e] = (unsigned short)f2bf(v);
}

// --- 3. flag reset: 64 lstm flags + 256 em flags ---------------------------
__global__ void zero_flags(unsigned int* __restrict__ f) {
  int i = threadIdx.x;
  if (i < 320) {
    unsigned z = 0u;
    asm volatile("global_store_dword %0, %1, off sc1"
                 :: "v"(f + i), "v"(z) : "memory");
  }
}

// --- 4. fused persistent kernel ---------------------------------------------
#define SBAR __builtin_amdgcn_sched_barrier(0)
#define WAITV(N) do { asm volatile("s_waitcnt vmcnt(" #N ")" ::: "memory"); SBAR; } while (0)
#define LDN(dst, ptr, OFF) \
  asm volatile("global_load_dwordx4 %0, %1, off offset:" OFF \
               : "=v"(dst) : "v"(ptr) : "memory")

#define ISSUE_X(B, P) do { \
  LDN(B[0],P,"0");   LDN(B[1],P,"32");  LDN(B[2],P,"64");  LDN(B[3],P,"96"); \
  LDN(B[4],P,"128"); LDN(B[5],P,"160"); LDN(B[6],P,"192"); LDN(B[7],P,"224"); \
  LDN(B[8],P,"256"); LDN(B[9],P,"288"); LDN(B[10],P,"320"); LDN(B[11],P,"352"); \
  LDN(B[12],P,"384"); LDN(B[13],P,"416"); LDN(B[14],P,"448"); LDN(B[15],P,"480"); } while (0)
#define ISSUE_H1(B, P) do { \
  LDN(B[0],P,"512"); LDN(B[1],P,"544"); LDN(B[2],P,"576"); LDN(B[3],P,"608"); \
  LDN(B[4],P,"640"); LDN(B[5],P,"672"); LDN(B[6],P,"704"); LDN(B[7],P,"736"); \
  LDN(B[8],P,"768"); LDN(B[9],P,"800"); LDN(B[10],P,"832"); LDN(B[11],P,"864"); \
  LDN(B[12],P,"896"); LDN(B[13],P,"928"); LDN(B[14],P,"960"); LDN(B[15],P,"992"); } while (0)

#define GATES_STORE(T) do { \
    bool mk = ((int)wxv) > 0; \
    _Pragma("unroll") \
    for (int r = 0; r < 4; ++r) { \
      float zi = acc[r], zf = acc[4 + r], zg = acc[8 + r], zo = acc[12 + r]; \
      float cn = sigm(zf) * cst[r] + sigm(zi) * tanh_fast(zg); \
      float hn = sigm(zo) * tanh_fast(cn); \
      if (mk) { cst[r] = cn; hst[r] = hn; } \
    } \
    u32x2 ph; \
    ph[0] = f2bf(hst[0]) | (f2bf(hst[1]) << 16); \
    ph[1] = f2bf(hst[2]) | (f2bf(hst[3]) << 16); \
    asm volatile("global_store_dwordx2 %0, %1, off sc1" \
                 :: "v"(hstore + (size_t)(T) * 65536), "v"(ph) : "memory"); \
  } while (0)

__global__ __launch_bounds__(128, 1) void fused_kernel(
    const unsigned short* __restrict__ x,      // [T][64][256] bf16
    unsigned short* __restrict__ hs,           // [256][64][512] bf16 (slot t = h[t+1])
    const unsigned short* __restrict__ WcatT,  // [2048][768] bf16
    const unsigned short* __restrict__ WoutT,  // [128][512] bf16
    const float* __restrict__ bias,            // [2048]
    const float* __restrict__ bout,            // [128]
    const float* __restrict__ trans,           // [128][128]
    const int* __restrict__ wx,                // [64][256]
    const int* __restrict__ y,                 // [64][257]
    float* __restrict__ em,                    // [16384][128] f32
    unsigned int* __restrict__ flags,          // [64] lstm flags
    unsigned int* __restrict__ emflag,         // [256] em flags
    float* __restrict__ out) {                 // [64]
  __shared__ float s_tl[KK][129];
  __shared__ float s_El[KK][129];
  __shared__ float s_p[KK];
  __shared__ float s_red[16];

  const int bid = blockIdx.x;
  const int tid = threadIdx.x;
  const int wave = tid >> 6, lane = tid & 63;

  if (bid < 64) {
    // ================= LSTM role (r13 verbatim) =================
    const int bhalf = wave;
    const int hi = lane >> 5;
    const int batch = bhalf * 32 + (lane & 31);
    const int u0 = bid * 8;
    const int rr = lane & 31;
    const int wcol = (rr >> 3) * HH + u0 + (rr & 7);

    bf16x8 wreg[48];
#pragma unroll
    for (int kf = 0; kf < 48; ++kf)
      wreg[kf] = *(const bf16x8*)(WcatT + (size_t)wcol * KCAT + kf * 16 + hi * 8);

    float bv[16];
#pragma unroll
    for (int q = 0; q < 4; ++q)
#pragma unroll
      for (int r = 0; r < 4; ++r)
        bv[q * 4 + r] = bias[q * HH + u0 + 4 * hi + r];

    const char* xlane  = (const char*)x  + ((size_t)batch * EE + hi * 8) * 2;
    const char* hread  = (const char*)hs + ((size_t)batch * HH + hi * 8) * 2;
    char*       hstore = (char*)hs + ((size_t)batch * HH + u0 + 4 * hi) * 2;
    const int*  wxp    = wx + batch * T_LEN;

    float cst[4] = {0.f, 0.f, 0.f, 0.f};
    float hst[4] = {0.f, 0.f, 0.f, 0.f};
    u32x4 bufX[16], bufH[16];
    unsigned wxv;
    f32x16 acc;

    // ---- t = 0 ----
    ISSUE_X(bufX, xlane);
    asm volatile("global_load_dword %0, %1, off" : "=v"(wxv) : "v"(wxp) : "memory");
    WAITV(0);
#pragma unroll
    for (int i = 0; i < 16; ++i) acc[i] = bv[i];
#pragma unroll
    for (int kf = 0; kf < 16; ++kf)
      acc = __builtin_amdgcn_mfma_f32_32x32x16_bf16(wreg[kf], ubf(bufX[kf]), acc, 0, 0, 0);
    GATES_STORE(0);
    WAITV(0);
    __syncthreads();
    if (tid == 0)
      __hip_atomic_store(flags + bid, 1u, __ATOMIC_RELAXED, __HIP_MEMORY_SCOPE_AGENT);

    // ---- t = 1..255 ----
    for (int t = 1; t < T_LEN; ++t) {
      const char* xt = xlane + (size_t)t * 32768;
      const char* hp = hread + (size_t)(t - 1) * 65536;

      ISSUE_X(bufX, xt);
      asm volatile("global_load_dword %0, %1, off" : "=v"(wxv) : "v"(wxp + t) : "memory");
      {
        unsigned v;
        do {
          asm volatile("global_load_dword %0, %1, off sc1\n\ts_waitcnt vmcnt(0)"
                       : "=v"(v) : "v"(flags + lane) : "memory");
        } while (!__all((int)(v >= (unsigned)t)));
        SBAR;
      }
      ISSUE_X(bufH, hp);                       // h chunk 0 (plain, L2-shared)
#pragma unroll
      for (int i = 0; i < 16; ++i) acc[i] = bv[i];
#pragma unroll
      for (int kf = 0; kf < 16; ++kf)
        acc = __builtin_amdgcn_mfma_f32_32x32x16_bf16(wreg[kf], ubf(bufX[kf]), acc, 0, 0, 0);
      SBAR;
      ISSUE_H1(bufX, hp);                      // h chunk 1 reuses x buffer
      WAITV(16);
#pragma unroll
      for (int kf = 0; kf < 16; ++kf)
        acc = __builtin_amdgcn_mfma_f32_32x32x16_bf16(wreg[16 + kf], ubf(bufH[kf]), acc, 0, 0, 0);
      WAITV(0);
#pragma unroll
      for (int kf = 0; kf < 16; ++kf)
        acc = __builtin_amdgcn_mfma_f32_32x32x16_bf16(wreg[32 + kf], ubf(bufX[kf]), acc, 0, 0, 0);
      GATES_STORE(t);
      WAITV(0);
      __syncthreads();
      if (tid == 0)
        __hip_atomic_store(flags + bid, (unsigned)(t + 1),
                           __ATOMIC_RELAXED, __HIP_MEMORY_SCOPE_AGENT);
    }
  } else if (bid < 72) {
    // ================= EM role: t = (bid-64) + 8*i =================
    const int et0 = bid - 64;
    const int arow = lane & 15, kg4 = (lane >> 4) * 8;
    for (int i = 0; i < 32; ++i) {
      const int t = et0 + 8 * i;
      {
        unsigned v; int it = 0;
        for (;;) {
          asm volatile("global_load_dword %0, %1, off sc1\n\ts_waitcnt vmcnt(0)"
                       : "=v"(v) : "v"(flags + lane) : "memory");
          if (__all((int)(v >= (unsigned)(t + 1)))) break;
          if (++it >= (1 << 17)) break;        // fail visibly, never hang
        }
        SBAR;
      }
      const unsigned short* A0 = hs + ((size_t)t * BB + wave * 32 + arow) * HH + kg4;
      f32x4 acc2[2][8];
#pragma unroll
      for (int mt = 0; mt < 2; ++mt)
#pragma unroll
        for (int nt = 0; nt < 8; ++nt) acc2[mt][nt] = (f32x4){0.f, 0.f, 0.f, 0.f};
#pragma unroll
      for (int ks = 0; ks < 16; ++ks) {
        bf16x8 a0 = *(const bf16x8*)(A0 + ks * 32);
        bf16x8 a1 = *(const bf16x8*)(A0 + 16 * HH + ks * 32);
#pragma unroll
        for (int nt = 0; nt < 8; ++nt) {
          bf16x8 bf = *(const bf16x8*)(WoutT + (size_t)(nt * 16 + arow) * HH + kg4 + ks * 32);
          acc2[0][nt] = __builtin_amdgcn_mfma_f32_16x16x32_bf16(a0, bf, acc2[0][nt], 0, 0, 0);
          acc2[1][nt] = __builtin_amdgcn_mfma_f32_16x16x32_bf16(a1, bf, acc2[1][nt], 0, 0, 0);
        }
      }
      // store em[t] (no mask: masked-off entries are never read)
#pragma unroll
      for (int nt = 0; nt < 8; ++nt) {
        int n = nt * 16 + arow;
        float bo = bout[n];
#pragma unroll
        for (int mt = 0; mt < 2; ++mt)
#pragma unroll
          for (int r = 0; r < 4; ++r) {
            int row = t * BB + wave * 32 + mt * 16 + (lane >> 4) * 4 + r;
            float val = acc2[mt][nt][r] + bo;
            asm volatile("global_store_dword %0, %1, off sc1"
                         :: "v"(em + (size_t)row * KK + n), "v"(val) : "memory");
          }
      }
      WAITV(0);
      __syncthreads();
      if (tid == 0)
        __hip_atomic_store(emflag + t, 1u, __ATOMIC_RELAXED, __HIP_MEMORY_SCOPE_AGENT);
    }
  } else {
    // ================= CRF role: b = bid - 72 =================
    const int b = bid - 72;
    const int k = tid;                         // 0..127
    for (int i2 = tid; i2 < KK * KK; i2 += 128) {
      float v = trans[i2];
      s_tl[i2 >> 7][i2 & 127] = v;
      s_El[i2 >> 7][i2 & 127] = __expf(v);     // exp(-1e4) = 0
    }
    __syncthreads();
    float sck = (k == 1) ? 0.f : -10000.f;
    float msc = 0.f;

    for (int t = 0; t < T_LEN; ++t) {
      if (wx[b * T_LEN + t] <= 0) continue;    // block-uniform
      {
        unsigned v; int it = 0;
        for (;;) {
          asm volatile("global_load_dword %0, %1, off sc1\n\ts_waitcnt vmcnt(0)"
                       : "=v"(v) : "v"(emflag + t) : "memory");
          if (v) break;
          if (++it >= (1 << 17)) break;        // fail visibly, never hang
        }
        SBAR;
      }
      s_p[k] = __expf(sck - msc);
      __syncthreads();
      float S = 0.f;
#pragma unroll
      for (int j = 0; j < KK; ++j) S += s_El[k][j] * s_p[j];
      float ns = em[((size_t)t * BB + b) * KK + k] + msc + __logf(S);
      sck = ns;
      float m = ns;
#pragma unroll
      for (int off = 32; off; off >>= 1) m = fmaxf(m, __shfl_xor(m, off));
      if (lane == 0) s_red[8 + wave] = m;
      __syncthreads();                         // also guards s_p reuse next step
      msc = fmaxf(s_red[8], s_red[9]);
    }

    // gold score (all needed em[t] already flagged during the loop)
    float term = 0.f, cnt = 0.f;
#pragma unroll
    for (int rep = 0; rep < 2; ++rep) {
      int tt = tid + rep * 128;
      int yp = y[b * 257 + tt], yn = y[b * 257 + tt + 1];
      if (wx[b * T_LEN + tt] > 0) {
        term += em[((size_t)tt * BB + b) * KK + yn] + s_tl[yn][yp];
        cnt += 1.f;
      }
    }
#pragma unroll
    for (int off = 32; off; off >>= 1) {
      term += __shfl_xor(term, off);
      cnt += __shfl_xor(cnt, off);
    }
    if (lane == 0) { s_red[wave] = term; s_red[2 + wave] = cnt; }
    __syncthreads();
    float gold = s_red[0] + s_red[1];
    int len = (int)(s_red[2] + s_red[3] + 0.5f);

    // Z = LSE_k(sc[k] + trans[EOS][k])
    float v = sck + s_tl[2][k];
    float mz = v;
#pragma unroll
    for (int off = 32; off; off >>= 1) mz = fmaxf(mz, __shfl_xor(mz, off));
    if (lane == 0) s_red[4 + wave] = mz;
    __syncthreads();
    mz = fmaxf(s_red[4], s_red[5]);
    float e = __expf(v - mz);
#pragma unroll
    for (int off = 32; off; off >>= 1) e += __shfl_xor(e, off);
    if (lane == 0) s_red[6 + wave] = e;
    __syncthreads();
    if (tid == 0) {
      float Z = mz + __logf(s_red[6] + s_red[7]);
      int last_tag = y[b * 257 + len];
      out[b] = Z - (gold + s_tl[2][last_tag]);
    }
  }
}

// ---------------------------------------------------------------------------
extern "C" void kernel_launch(void* const* d_in, const int* in_sizes, int n_in,
                              void* d_out, int out_size, void* d_ws, size_t ws_size,
                              hipStream_t stream) {
  const int*   cx    = (const int*)d_in[0];
  const int*   wx    = (const int*)d_in[1];
  const int*   y     = (const int*)d_in[2];
  const float* ce    = (const float*)d_in[3];
  const float* we    = (const float*)d_in[4];
  const float* Wi    = (const float*)d_in[5];
  const float* Wh    = (const float*)d_in[6];
  const float* bias  = (const float*)d_in[7];
  const float* Wout  = (const float*)d_in[8];
  const float* bout  = (const float*)d_in[9];
  const float* trans = (const float*)d_in[10];
  float* out = (float*)d_out;

  char* ws = (char*)d_ws;
  // ws layout (16B aligned), ~37 MB (em no longer aliases x — written while
  // lstm still reads x)
  unsigned short* WcatT = (unsigned short*)(ws + 0);          //  3,145,728
  unsigned short* WoutT = (unsigned short*)(ws + 3145728);    //    131,072
  unsigned short* x     = (unsigned short*)(ws + 3276800);    //  8,388,608
  unsigned short* hs    = (unsigned short*)(ws + 11665408);   // 16,777,216
  unsigned int*   flags = (unsigned int*)(ws + 28442624);     //  64 dwords
  unsigned int*   emflag= (unsigned int*)(ws + 28442880);     // 256 dwords
  float*          em    = (float*)(ws + 28444672);            //  8,388,608

  build_wcat<<<384, 256, 0, stream>>>(Wi, Wh, WcatT);
  build_wout<<<16, 256, 0, stream>>>(Wout, WoutT);
  embed_kernel<<<T_LEN * BB, 256, 0, stream>>>(wx, cx, we, ce, x);
  zero_flags<<<1, 320, 0, stream>>>(flags);
  fused_kernel<<<136, 128, 0, stream>>>(x, hs, WcatT, WoutT, bias, bout, trans,
                                        wx, y, em, flags, emflag, out);
}